// Round 1
// baseline (1640.277 us; speedup 1.0000x reference)
//
#include <hip/hip_runtime.h>
#include <math.h>

#define HH 160
#define WW 160
#define HWSZ 25600
#define CCH 64

// ---------------------------------------------------------------------------
// prep: fold BN params into scale/shift for both BN layers
// sc layout: [0:64) scale1, [64:128) shift1, [128:192) scale2, [192:256) shift2
__global__ __launch_bounds__(64) void prep_kernel(
    const float* __restrict__ g1, const float* __restrict__ b1,
    const float* __restrict__ m1, const float* __restrict__ v1,
    const float* __restrict__ g2, const float* __restrict__ b2,
    const float* __restrict__ m2, const float* __restrict__ v2,
    float* __restrict__ sc) {
  int t = threadIdx.x;  // 64 threads
  float s1 = g1[t] * rsqrtf(v1[t] + 1e-5f);
  sc[t]       = s1;
  sc[64 + t]  = b1[t] - m1[t] * s1;
  float s2 = g2[t] * rsqrtf(v2[t] + 1e-5f);
  sc[128 + t] = s2;
  sc[192 + t] = b2[t] - m2[t] * s2;
}

// ---------------------------------------------------------------------------
// conv27: 3x3 conv, 64 -> 27 channels, pad 1, + bias.  in: [B][64][H][W]
// w: [27][64][3][3], out: [B][27][H][W]
// Block: 256 thr = 32x8 pixel tile. LDS stages 8 input channels at a time.
__global__ __launch_bounds__(256) void conv27_kernel(
    const float* __restrict__ in, const float* __restrict__ w,
    const float* __restrict__ bias, float* __restrict__ om) {
  __shared__ float tin[8][10][34];
  int t  = threadIdx.x;
  int tx = t & 31, ty = t >> 5;
  int x0 = blockIdx.x * 32, y0 = blockIdx.y * 8;
  int b  = blockIdx.z;

  float acc[27];
#pragma unroll
  for (int j = 0; j < 27; j++) acc[j] = 0.f;

  const float* inb = in + (size_t)b * CCH * HWSZ;

  for (int cc = 0; cc < 8; cc++) {
    // stage 8 channels x 10 x 34 halo tile (zero-padded borders)
    for (int i = t; i < 2720; i += 256) {
      int c  = i / 340;
      int r  = i - c * 340;
      int ly = r / 34;
      int lx = r - ly * 34;
      int gy = y0 - 1 + ly, gx = x0 - 1 + lx;
      float v = 0.f;
      if (gy >= 0 && gy < HH && gx >= 0 && gx < WW)
        v = inb[(cc * 8 + c) * HWSZ + gy * WW + gx];
      tin[c][ly][lx] = v;
    }
    __syncthreads();

#pragma unroll
    for (int c = 0; c < 8; c++) {
      float v[9];
#pragma unroll
      for (int ky = 0; ky < 3; ky++)
#pragma unroll
        for (int kx = 0; kx < 3; kx++)
          v[ky * 3 + kx] = tin[c][ty + ky][tx + kx];
      const float* wp = w + (cc * 8 + c) * 9;  // + j*576 + kk
#pragma unroll
      for (int j = 0; j < 27; j++) {
#pragma unroll
        for (int kk = 0; kk < 9; kk++)
          acc[j] += v[kk] * wp[j * 576 + kk];
      }
    }
    __syncthreads();
  }

  int gy = y0 + ty, gx = x0 + tx;
  float* op = om + (size_t)b * 27 * HWSZ + gy * WW + gx;
#pragma unroll
  for (int j = 0; j < 27; j++) op[j * HWSZ] = acc[j] + bias[j];
}

// ---------------------------------------------------------------------------
// dcn: modulated deformable conv (64->64, 3x3) + BN + optional residual + GELU
// xin: [B][64][H][W] (sampled tensor), om: [B][27][H][W] (raw conv output:
// ch 2k = dy_k, ch 2k+1 = dx_k, ch 18+k = mask logit), w: [64][576],
// identity: residual input or null, out: [B][64][H][W].
// Block: 256 thr, 16 consecutive x-pixels of one row.
__global__ __launch_bounds__(256) void dcn_kernel(
    const float* __restrict__ xin, const float* __restrict__ om,
    const float* __restrict__ w, const float* __restrict__ scale,
    const float* __restrict__ shift, const float* __restrict__ identity,
    float* __restrict__ out) {
  __shared__ float meta_w[9][16][4];  // corner weight * validity * mask
  __shared__ int   meta_o[9][16][4];  // clamped linear offset y*W+x
  __shared__ float samp[16][580];     // [px][ck], ck = c*9+k, pad to 580

  int t  = threadIdx.x;
  int x0 = blockIdx.x * 16;
  int y  = blockIdx.y;
  int b  = blockIdx.z;

  // ---- phase 0: sampling metadata (one thread per (k, px)) ----
  if (t < 144) {
    int k = t >> 4, p = t & 15;
    int x = x0 + p;
    const float* omb = om + (size_t)b * 27 * HWSZ + y * WW + x;
    float dy = omb[(2 * k) * HWSZ];
    float dx = omb[(2 * k + 1) * HWSZ];
    float ml = omb[(18 + k) * HWSZ];
    float m  = 1.f / (1.f + expf(-ml));
    int ki = k / 3, kj = k - ki * 3;
    float py = (float)(y - 1 + ki) + dy;
    float px = (float)(x - 1 + kj) + dx;
    float fy = floorf(py), fx = floorf(px);
    float ly = py - fy, lx = px - fx;
    int yi0 = (int)fy, xi0 = (int)fx;
#pragma unroll
    for (int j = 0; j < 4; j++) {
      int yi = yi0 + (j >> 1), xi = xi0 + (j & 1);
      float wy = (j >> 1) ? ly : 1.f - ly;
      float wx = (j & 1) ? lx : 1.f - lx;
      bool valid = (yi >= 0) && (yi < HH) && (xi >= 0) && (xi < WW);
      int yc = min(max(yi, 0), HH - 1);
      int xc = min(max(xi, 0), WW - 1);
      meta_w[k][p][j] = valid ? wy * wx * m : 0.f;
      meta_o[k][p][j] = yc * WW + xc;
    }
  }
  __syncthreads();

  // ---- phase 1: bilinear gather into samp[px][ck] ----
  {
    const float* xb = xin + (size_t)b * CCH * HWSZ;
    int p  = t & 15;
    int tg = t >> 4;
    for (int i = 0; i < 36; i++) {
      int ck = i * 16 + tg;  // 0..575
      int c  = ck / 9;
      int k  = ck - c * 9;
      const float* xcp = xb + c * HWSZ;
      float a = meta_w[k][p][0] * xcp[meta_o[k][p][0]] +
                meta_w[k][p][1] * xcp[meta_o[k][p][1]] +
                meta_w[k][p][2] * xcp[meta_o[k][p][2]] +
                meta_w[k][p][3] * xcp[meta_o[k][p][3]];
      samp[p][ck] = a;
    }
  }
  __syncthreads();

  // ---- phase 2: 576-deep GEMM, thread = (px, 4 out channels) ----
  {
    int p2 = t & 15, og = t >> 4;
    const float* w0p = w + (og * 4 + 0) * 576;
    const float* w1p = w0p + 576;
    const float* w2p = w1p + 576;
    const float* w3p = w2p + 576;
    float a0 = 0.f, a1 = 0.f, a2 = 0.f, a3 = 0.f;
#pragma unroll 4
    for (int q = 0; q < 144; q++) {
      float4 s  = *(const float4*)(&samp[p2][q * 4]);
      float4 u0 = *(const float4*)(w0p + q * 4);
      float4 u1 = *(const float4*)(w1p + q * 4);
      float4 u2 = *(const float4*)(w2p + q * 4);
      float4 u3 = *(const float4*)(w3p + q * 4);
      a0 += s.x * u0.x + s.y * u0.y + s.z * u0.z + s.w * u0.w;
      a1 += s.x * u1.x + s.y * u1.y + s.z * u1.z + s.w * u1.w;
      a2 += s.x * u2.x + s.y * u2.y + s.z * u2.z + s.w * u2.w;
      a3 += s.x * u3.x + s.y * u3.y + s.z * u3.z + s.w * u3.w;
    }

    // ---- epilogue: BN + optional residual + exact GELU ----
    int xg = x0 + p2;
    float av[4] = {a0, a1, a2, a3};
#pragma unroll
    for (int j = 0; j < 4; j++) {
      int o = og * 4 + j;
      size_t idx = ((size_t)(b * CCH + o)) * HWSZ + y * WW + xg;
      float v = av[j] * scale[o] + shift[o];
      if (identity) v += identity[idx];
      v = 0.5f * v * (1.f + erff(v * 0.70710678118654752f));
      out[idx] = v;
    }
  }
}

// ---------------------------------------------------------------------------
extern "C" void kernel_launch(void* const* d_in, const int* in_sizes, int n_in,
                              void* d_out, int out_size, void* d_ws, size_t ws_size,
                              hipStream_t stream) {
  const float* x     = (const float*)d_in[0];
  const float* w_om1 = (const float*)d_in[1];
  const float* b_om1 = (const float*)d_in[2];
  const float* w_d1  = (const float*)d_in[3];
  const float* bn1g  = (const float*)d_in[4];
  const float* bn1b  = (const float*)d_in[5];
  const float* bn1m  = (const float*)d_in[6];
  const float* bn1v  = (const float*)d_in[7];
  const float* w_om2 = (const float*)d_in[8];
  const float* b_om2 = (const float*)d_in[9];
  const float* w_d2  = (const float*)d_in[10];
  const float* bn2g  = (const float*)d_in[11];
  const float* bn2b  = (const float*)d_in[12];
  const float* bn2m  = (const float*)d_in[13];
  const float* bn2v  = (const float*)d_in[14];

  float* ws   = (float*)d_ws;
  float* om   = ws;                       // 4*27*25600 = 2,764,800 floats
  float* out1 = ws + 2764800;             // 4*64*25600 = 6,553,600 floats
  float* sc   = ws + 2764800 + 6553600;   // 256 floats
  float* outp = (float*)d_out;

  prep_kernel<<<dim3(1), dim3(64), 0, stream>>>(bn1g, bn1b, bn1m, bn1v,
                                                bn2g, bn2b, bn2m, bn2v, sc);

  dim3 cgrid(WW / 32, HH / 8, 4);
  dim3 dgrid(WW / 16, HH, 4);

  // layer 1
  conv27_kernel<<<cgrid, dim3(256), 0, stream>>>(x, w_om1, b_om1, om);
  dcn_kernel<<<dgrid, dim3(256), 0, stream>>>(x, om, w_d1, sc, sc + 64,
                                              nullptr, out1);
  // layer 2
  conv27_kernel<<<cgrid, dim3(256), 0, stream>>>(out1, w_om2, b_om2, om);
  dcn_kernel<<<dgrid, dim3(256), 0, stream>>>(out1, om, w_d2, sc + 128, sc + 192,
                                              x, outp);
}

// Round 2
// 505.627 us; speedup vs baseline: 3.2440x; 3.2440x over previous
//
#include <hip/hip_runtime.h>
#include <math.h>

#define HH 160
#define WW 160
#define HWSZ 25600
#define CCH 64
#define SSTR 296  // samp row stride in shorts: 592B = 37*16B (aligned) ; 148 dwords %32=20=4*odd -> 2-way banks (free)

typedef __attribute__((ext_vector_type(8))) short short8;
typedef __attribute__((ext_vector_type(4))) float f32x4;

__device__ __forceinline__ unsigned short f2bf(float f) {
  union { float f; unsigned int u; } v; v.f = f;
  unsigned int r = v.u + 0x7FFFu + ((v.u >> 16) & 1u);
  return (unsigned short)(r >> 16);
}
__device__ __forceinline__ float bf2f(unsigned short b) {
  union { float f; unsigned int u; } v; v.u = ((unsigned int)b) << 16;
  return v.f;
}

// ---------------------------------------------------------------------------
// prep: BN fold + convert all weights to bf16
__global__ __launch_bounds__(256) void prep_kernel(
    const float* __restrict__ g1, const float* __restrict__ b1,
    const float* __restrict__ m1, const float* __restrict__ v1,
    const float* __restrict__ g2, const float* __restrict__ b2,
    const float* __restrict__ m2, const float* __restrict__ v2,
    const float* __restrict__ wd1, const float* __restrict__ wd2,
    const float* __restrict__ wo1, const float* __restrict__ wo2,
    float* __restrict__ sc, unsigned short* __restrict__ w1b,
    unsigned short* __restrict__ w2b, unsigned short* __restrict__ wo1b,
    unsigned short* __restrict__ wo2b) {
  int i = blockIdx.x * 256 + threadIdx.x;
  int stride = gridDim.x * 256;
  for (int j = i; j < 36864; j += stride) {
    w1b[j] = f2bf(wd1[j]);
    w2b[j] = f2bf(wd2[j]);
  }
  for (int j = i; j < 18432; j += stride) {  // 32 rows, zero-pad oc 27..31
    int oc = j / 576;
    wo1b[j] = (oc < 27) ? f2bf(wo1[j]) : 0;
    wo2b[j] = (oc < 27) ? f2bf(wo2[j]) : 0;
  }
  if (i < 64) {
    float s1 = g1[i] * rsqrtf(v1[i] + 1e-5f);
    sc[i]       = s1;
    sc[64 + i]  = b1[i] - m1[i] * s1;
    float s2 = g2[i] * rsqrtf(v2[i] + 1e-5f);
    sc[128 + i] = s2;
    sc[192 + i] = b2[i] - m2[i] * s2;
  }
}

// ---------------------------------------------------------------------------
// conv27: 3x3 conv 64->27 (+bias) via bf16 MFMA im2col GEMM.
// Block: 256 thr = 4 waves, px tile 16x * 4y (64 px). K=576 in 2 chunks of 288.
__global__ __launch_bounds__(256, 3) void conv27_kernel(
    const float* __restrict__ in, const unsigned short* __restrict__ wb,
    const float* __restrict__ bias, float* __restrict__ om) {
  __shared__ __align__(16) short samp[64][SSTR];  // [px][k'] bf16

  int t = threadIdx.x;
  int w = t >> 6, lane = t & 63;
  int x0 = blockIdx.x * 16, y0 = blockIdx.y * 4;
  int b = blockIdx.z;
  int row = lane >> 4, col = lane & 15;
  int quad = lane >> 4, m = lane & 15;

  // A-frags: wave mtile = w&1 -> oc0; lane holds A[oc0+m][s*32+quad*8 + j]
  int oc0 = 16 * (w & 1);
  short8 af[18];
#pragma unroll
  for (int s = 0; s < 18; s++)
    af[s] = *(const short8*)&wb[(oc0 + m) * 576 + s * 32 + quad * 8];

  const float* xb = in + (size_t)b * CCH * HWSZ;
  int lin = (y0 + row) * WW + (x0 + col);

  f32x4 acc[2] = {};
  int nbase = (w >> 1) * 2;  // this wave's two n-tiles

  for (int cc = 0; cc < 2; cc++) {
    if (cc) __syncthreads();
    // gather: this wave fills channels [cc*32+8w, +8), all 9 taps, lane = px
    for (int k = 0; k < 9; k++) {
      int ki = k / 3, kj = k - ki * 3;
      int yy = y0 + row + ki - 1;
      int xx = x0 + col + kj - 1;
      bool valid = (yy >= 0) && (yy < HH) && (xx >= 0) && (xx < WW);
      int off = lin + (ki - 1) * WW + (kj - 1);
      off = min(max(off, 0), HWSZ - 1);
      const float* xc = xb + (cc * 32 + 8 * w) * HWSZ;
      int sidx = (8 * w) * 9 + k;
#pragma unroll
      for (int c8 = 0; c8 < 8; c8++) {
        float v = xc[off];
        v = valid ? v : 0.f;
        samp[lane][sidx] = (short)f2bf(v);
        xc += HWSZ;
        sidx += 9;
      }
    }
    __syncthreads();
#pragma unroll
    for (int s = 0; s < 9; s++) {
#pragma unroll
      for (int nt = 0; nt < 2; nt++) {
        short8 bf = *(const short8*)&samp[(nbase + nt) * 16 + m][s * 32 + quad * 8];
        acc[nt] = __builtin_amdgcn_mfma_f32_16x16x32_bf16(af[cc * 9 + s], bf,
                                                          acc[nt], 0, 0, 0);
      }
    }
  }

  // store: D[m=quad*4+r][n=lane&15]
#pragma unroll
  for (int nt = 0; nt < 2; nt++) {
    int yy = y0 + nbase + nt, xx = x0 + m;
#pragma unroll
    for (int r = 0; r < 4; r++) {
      int oc = oc0 + quad * 4 + r;
      if (oc < 27)
        om[((size_t)(b * 27 + oc)) * HWSZ + yy * WW + xx] = acc[nt][r] + bias[oc];
    }
  }
}

// ---------------------------------------------------------------------------
// dcn: modulated deformable conv 64->64 via bf16 MFMA + BN + residual + GELU.
// Block: 256 thr = 4 waves, px tile 16x * 4y. Wave w owns oc [16w,16w+16).
__global__ __launch_bounds__(256, 3) void dcn_kernel(
    const float* __restrict__ xin, const float* __restrict__ om,
    const unsigned short* __restrict__ wb, const float* __restrict__ scale,
    const float* __restrict__ shift, const float* __restrict__ identity,
    float* __restrict__ out) {
  __shared__ __align__(16) short samp[64][SSTR];          // [px][k'] bf16
  __shared__ __align__(16) unsigned short meta[9][64][8]; // o0..o3, w0..w3(bf16)

  int t = threadIdx.x;
  int w = t >> 6, lane = t & 63;
  int x0 = blockIdx.x * 16, y0 = blockIdx.y * 4;
  int b = blockIdx.z;
  int quad = lane >> 4, m = lane & 15;

  // A-frags (weights held in VGPRs for whole kernel)
  int oc0 = 16 * w;
  short8 af[18];
#pragma unroll
  for (int s = 0; s < 18; s++)
    af[s] = *(const short8*)&wb[(oc0 + m) * 576 + s * 32 + quad * 8];

  // meta: per (k, px) fold bilinear corner weights * validity * sigmoid(mask)
  for (int i = t; i < 576; i += 256) {
    int px = i & 63, k = i >> 6;
    int y = y0 + (px >> 4), x = x0 + (px & 15);
    const float* omb = om + ((size_t)b * 27) * HWSZ + y * WW + x;
    float dy = omb[(2 * k) * HWSZ];
    float dx = omb[(2 * k + 1) * HWSZ];
    float ml = omb[(18 + k) * HWSZ];
    float msk = 1.f / (1.f + __expf(-ml));
    int ki = k / 3, kj = k - ki * 3;
    float py = (float)(y - 1 + ki) + dy;
    float pxf = (float)(x - 1 + kj) + dx;
    float fy = floorf(py), fx = floorf(pxf);
    float ly = py - fy, lx = pxf - fx;
    int yi0 = (int)fy, xi0 = (int)fx;
    union { unsigned short u[8]; short8 v8; } pack;
#pragma unroll
    for (int j = 0; j < 4; j++) {
      int yi = yi0 + (j >> 1), xi = xi0 + (j & 1);
      float wy = (j >> 1) ? ly : 1.f - ly;
      float wx = (j & 1) ? lx : 1.f - lx;
      bool valid = (yi >= 0) && (yi < HH) && (xi >= 0) && (xi < WW);
      int yc = min(max(yi, 0), HH - 1);
      int xc = min(max(xi, 0), WW - 1);
      pack.u[j] = (unsigned short)(yc * WW + xc);
      pack.u[4 + j] = valid ? f2bf(wy * wx * msk) : 0;
    }
    *(short8*)&meta[k][px][0] = pack.v8;
  }
  __syncthreads();

  const float* xb = xin + (size_t)b * CCH * HWSZ;
  f32x4 acc[4] = {};

  for (int cc = 0; cc < 2; cc++) {
    if (cc) __syncthreads();
    // gather: wave fills channels [cc*32+8w, +8) x 9 taps, lane = px
    for (int k = 0; k < 9; k++) {
      short8 mv = *(const short8*)&meta[k][lane][0];
      int o0 = (unsigned short)mv[0], o1 = (unsigned short)mv[1];
      int o2 = (unsigned short)mv[2], o3 = (unsigned short)mv[3];
      float w0 = bf2f((unsigned short)mv[4]), w1 = bf2f((unsigned short)mv[5]);
      float w2 = bf2f((unsigned short)mv[6]), w3 = bf2f((unsigned short)mv[7]);
      const float* xc = xb + (cc * 32 + 8 * w) * HWSZ;
      int sidx = (8 * w) * 9 + k;
#pragma unroll
      for (int c8 = 0; c8 < 8; c8++) {
        float v = w0 * xc[o0] + w1 * xc[o1] + w2 * xc[o2] + w3 * xc[o3];
        samp[lane][sidx] = (short)f2bf(v);
        xc += HWSZ;
        sidx += 9;
      }
    }
    __syncthreads();
#pragma unroll
    for (int s = 0; s < 9; s++) {
#pragma unroll
      for (int nt = 0; nt < 4; nt++) {
        short8 bf = *(const short8*)&samp[nt * 16 + m][s * 32 + quad * 8];
        acc[nt] = __builtin_amdgcn_mfma_f32_16x16x32_bf16(af[cc * 9 + s], bf,
                                                          acc[nt], 0, 0, 0);
      }
    }
  }

  // epilogue: BN + optional residual + exact GELU. D[m=quad*4+r][n=lane&15]
#pragma unroll
  for (int nt = 0; nt < 4; nt++) {
    int yy = y0 + nt, xx = x0 + m;
#pragma unroll
    for (int r = 0; r < 4; r++) {
      int oc = oc0 + quad * 4 + r;
      size_t idx = ((size_t)(b * CCH + oc)) * HWSZ + yy * WW + xx;
      float v = acc[nt][r] * scale[oc] + shift[oc];
      if (identity) v += identity[idx];
      v = 0.5f * v * (1.f + erff(v * 0.70710678118654752f));
      out[idx] = v;
    }
  }
}

// ---------------------------------------------------------------------------
extern "C" void kernel_launch(void* const* d_in, const int* in_sizes, int n_in,
                              void* d_out, int out_size, void* d_ws, size_t ws_size,
                              hipStream_t stream) {
  const float* x     = (const float*)d_in[0];
  const float* w_om1 = (const float*)d_in[1];
  const float* b_om1 = (const float*)d_in[2];
  const float* w_d1  = (const float*)d_in[3];
  const float* bn1g  = (const float*)d_in[4];
  const float* bn1b  = (const float*)d_in[5];
  const float* bn1m  = (const float*)d_in[6];
  const float* bn1v  = (const float*)d_in[7];
  const float* w_om2 = (const float*)d_in[8];
  const float* b_om2 = (const float*)d_in[9];
  const float* w_d2  = (const float*)d_in[10];
  const float* bn2g  = (const float*)d_in[11];
  const float* bn2b  = (const float*)d_in[12];
  const float* bn2m  = (const float*)d_in[13];
  const float* bn2v  = (const float*)d_in[14];

  float* ws   = (float*)d_ws;
  float* om   = ws;                       // 4*27*25600 = 2,764,800 f
  float* out1 = ws + 2764800;             // 4*64*25600 = 6,553,600 f
  float* sc   = ws + 9318400;             // 256 f
  unsigned short* w1b  = (unsigned short*)(ws + 9318656);  // 36864 bf16
  unsigned short* w2b  = w1b + 36864;                      // 36864 bf16
  unsigned short* wo1b = w2b + 36864;                      // 32*576 bf16 (padded)
  unsigned short* wo2b = wo1b + 18432;
  float* outp = (float*)d_out;

  prep_kernel<<<dim3(64), dim3(256), 0, stream>>>(
      bn1g, bn1b, bn1m, bn1v, bn2g, bn2b, bn2m, bn2v,
      w_d1, w_d2, w_om1, w_om2, sc, w1b, w2b, wo1b, wo2b);

  dim3 grid(WW / 16, HH / 4, 4);

  // layer 1
  conv27_kernel<<<grid, dim3(256), 0, stream>>>(x, wo1b, b_om1, om);
  dcn_kernel<<<grid, dim3(256), 0, stream>>>(x, om, w1b, sc, sc + 64,
                                             nullptr, out1);
  // layer 2
  conv27_kernel<<<grid, dim3(256), 0, stream>>>(out1, wo2b, b_om2, om);
  dcn_kernel<<<grid, dim3(256), 0, stream>>>(out1, om, w2b, sc + 128, sc + 192,
                                             x, outp);
}

// Round 3
// 425.981 us; speedup vs baseline: 3.8506x; 1.1870x over previous
//
#include <hip/hip_runtime.h>
#include <math.h>

#define HH 160
#define WW 160
#define HWSZ 25600

typedef __attribute__((ext_vector_type(8))) short short8;
typedef __attribute__((ext_vector_type(8))) _Float16 half8;
typedef __attribute__((ext_vector_type(2))) _Float16 half2v;
typedef __attribute__((ext_vector_type(4))) float f32x4;

__device__ __forceinline__ short f2h(float f) {
  union { _Float16 h; short s; } u; u.h = (_Float16)f; return u.s;
}
__device__ __forceinline__ half2v bcast_h(short s) {
  unsigned int x = (unsigned short)s; x |= x << 16;
  union { unsigned int u; half2v h; } v; v.u = x; return v.h;
}

// ---------------------------------------------------------------------------
// prep: BN fold + reorder+convert weights to f16 MFMA A-fragment layout.
// dcn:  dst[f][ot(4)][m(16)][q(4)][j(8)] = w[ot*16+m][c*9+k], k'=f*32+q*8+j,
//       k=k'>>6, c=k'&63   (36864 halves)
// conv: dst[f][ot(2)][m][q][j] = (oc<27 ? w[oc*576+c*9+k] : 0)  (18432 halves)
__global__ __launch_bounds__(256) void prep_kernel(
    const float* __restrict__ g1, const float* __restrict__ b1,
    const float* __restrict__ m1, const float* __restrict__ v1,
    const float* __restrict__ g2, const float* __restrict__ b2,
    const float* __restrict__ m2, const float* __restrict__ v2,
    const float* __restrict__ wd1, const float* __restrict__ wd2,
    const float* __restrict__ wo1, const float* __restrict__ wo2,
    float* __restrict__ sc, short* __restrict__ wd1h, short* __restrict__ wd2h,
    short* __restrict__ wo1h, short* __restrict__ wo2h) {
  int i0 = blockIdx.x * 256 + threadIdx.x;
  int stride = gridDim.x * 256;
  for (int i = i0; i < 36864; i += stride) {
    int j = i & 7, q = (i >> 3) & 3, m = (i >> 5) & 15;
    int ot = (i >> 9) & 3, f = i >> 11;
    int kp = f * 32 + q * 8 + j;
    int k = kp >> 6, c = kp & 63;
    int src = (ot * 16 + m) * 576 + c * 9 + k;
    wd1h[i] = f2h(wd1[src]);
    wd2h[i] = f2h(wd2[src]);
  }
  for (int i = i0; i < 18432; i += stride) {
    int j = i & 7, q = (i >> 3) & 3, m = (i >> 5) & 15;
    int ot = (i >> 9) & 1, f = i >> 10;
    int kp = f * 32 + q * 8 + j;
    int k = kp >> 6, c = kp & 63;
    int oc = ot * 16 + m;
    float v1v = (oc < 27) ? wo1[oc * 576 + c * 9 + k] : 0.f;
    float v2v = (oc < 27) ? wo2[oc * 576 + c * 9 + k] : 0.f;
    wo1h[i] = f2h(v1v);
    wo2h[i] = f2h(v2v);
  }
  if (i0 < 64) {
    float s1 = g1[i0] * rsqrtf(v1[i0] + 1e-5f);
    sc[i0]       = s1;
    sc[64 + i0]  = b1[i0] - m1[i0] * s1;
    float s2 = g2[i0] * rsqrtf(v2[i0] + 1e-5f);
    sc[128 + i0] = s2;
    sc[192 + i0] = b2[i0] - m2[i0] * s2;
  }
}

// ---------------------------------------------------------------------------
// conv27: 3x3 conv 64->27 (+bias) via f16 MFMA. Block = 16x*4y px, 4 waves.
// LDS xtile [slot=ty*18+tx][8 groups of 8ch], 16B groups XOR-swizzled by slot&7.
__global__ __launch_bounds__(256, 4) void conv27_kernel(
    const float* __restrict__ in, const short* __restrict__ wh,
    const float* __restrict__ bias, float* __restrict__ om) {
  __shared__ short xt[108 * 64];  // 6x18 slots x 64ch f16 = 13.8 KB
  int t = threadIdx.x;
  int x0 = blockIdx.x * 16, y0 = blockIdx.y * 4;
  int b = blockIdx.z;
  const float* xb = in + (size_t)b * 64 * HWSZ;
  int ybase = y0 - 1, xbase = x0 - 1;

  for (int i = t; i < 864; i += 256) {
    int slot = i >> 3, g = i & 7;
    int ty = slot / 18, tx = slot - ty * 18;
    int gy = ybase + ty, gx = xbase + tx;
    bool inb = (gy >= 0) & (gy < HH) & (gx >= 0) & (gx < WW);
    int o = inb ? gy * WW + gx : 0;
    const float* xp = xb + (g * 8) * HWSZ + o;
    union { short8 s8; short s[8]; } pk;
#pragma unroll
    for (int j = 0; j < 8; j++) pk.s[j] = f2h(inb ? xp[j * HWSZ] : 0.f);
    *(short8*)&xt[slot * 64 + ((g ^ (slot & 7)) << 3)] = pk.s8;
  }
  __syncthreads();

  int w = t >> 6, lane = t & 63, q = lane >> 4, m = lane & 15;
  f32x4 acc0 = {}, acc1 = {};
#pragma unroll 3
  for (int k = 0; k < 9; k++) {
    int ki = k / 3, kj = k - ki * 3;
    int slotb = (w + ki) * 18 + m + kj;
#pragma unroll
    for (int ch = 0; ch < 2; ch++) {
      int f = 2 * k + ch;
      int g = ch * 4 + q;
      const short* ap = wh + (f * 128 + m * 4 + q) * 8;  // [f][2][16][4][8]
      short8 a0 = *(const short8*)ap;
      short8 a1 = *(const short8*)(ap + 512);
      short8 bf = *(const short8*)&xt[slotb * 64 + ((g ^ (slotb & 7)) << 3)];
      union { short8 s8; half8 h; } A0, A1, B;
      A0.s8 = a0; A1.s8 = a1; B.s8 = bf;
      acc0 = __builtin_amdgcn_mfma_f32_16x16x32_f16(A0.h, B.h, acc0, 0, 0, 0);
      acc1 = __builtin_amdgcn_mfma_f32_16x16x32_f16(A1.h, B.h, acc1, 0, 0, 0);
    }
  }
  int y = y0 + w, x = x0 + m;
  float* ob = om + (size_t)b * 27 * HWSZ + y * WW + x;
#pragma unroll
  for (int r = 0; r < 4; r++) {
    int oc = q * 4 + r;                       // < 16 always
    ob[oc * HWSZ] = acc0[r] + bias[oc];
    int oc2 = 16 + oc;
    if (oc2 < 27) ob[oc2 * HWSZ] = acc1[r] + bias[oc2];
  }
}

// ---------------------------------------------------------------------------
// dcn: modulated deformable conv 64->64 via f16 MFMA + BN + residual + GELU.
// LDS xtile: 12x24 slots (margin +-3 px for offsets; |off|max ~1.3) x 64 ch,
// f16, 16B groups XOR-swizzled. Bilinear runs in packed v_pk_fma_f16 straight
// into B-fragments (no intermediate sample buffer).
__global__ __launch_bounds__(256, 3) void dcn_kernel(
    const float* __restrict__ xin, const float* __restrict__ om,
    const short* __restrict__ wh, const float* __restrict__ scale,
    const float* __restrict__ shift, const float* __restrict__ identity,
    float* __restrict__ out) {
  __shared__ short xt[288 * 64];      // 36.9 KB
  __shared__ short meta[9 * 64 * 8];  // 9.2 KB: p00, w00,w01,w10,w11 (f16)
  int t = threadIdx.x;
  int x0 = blockIdx.x * 16, y0 = blockIdx.y * 4;
  int b = blockIdx.z;
  const float* xb = xin + (size_t)b * 64 * HWSZ;
  int ybase = y0 - 4, xbase = x0 - 4;

  // ---- stage xtile: 288 slots x 8 channel-groups ----
  for (int i = t; i < 2304; i += 256) {
    int slot = i >> 3, g = i & 7;
    int ty = slot / 24, tx = slot - ty * 24;
    int gy = ybase + ty, gx = xbase + tx;
    bool inb = (gy >= 0) & (gy < HH) & (gx >= 0) & (gx < WW);
    int o = inb ? gy * WW + gx : 0;
    const float* xp = xb + (g * 8) * HWSZ + o;
    union { short8 s8; short s[8]; } pk;
#pragma unroll
    for (int j = 0; j < 8; j++) pk.s[j] = f2h(inb ? xp[j * HWSZ] : 0.f);
    *(short8*)&xt[slot * 64 + ((g ^ (slot & 7)) << 3)] = pk.s8;
  }

  // ---- meta: per (k, px): top-left tile slot + 4 folded corner weights ----
  for (int i = t; i < 576; i += 256) {
    int k = i >> 6, px = i & 63;
    int y = y0 + (px >> 4), x = x0 + (px & 15);
    const float* omb = om + ((size_t)b * 27) * HWSZ + y * WW + x;
    float dy = omb[(2 * k) * HWSZ];
    float dx = omb[(2 * k + 1) * HWSZ];
    float ml = omb[(18 + k) * HWSZ];
    float msk = 1.f / (1.f + __expf(-ml));
    int ki = k / 3, kj = k - ki * 3;
    float py  = (float)(y - 1 + ki) + dy;
    float pxf = (float)(x - 1 + kj) + dx;
    float fy = floorf(py), fx = floorf(pxf);
    float ly = py - fy, lx = pxf - fx;
    int yi0 = (int)fy, xi0 = (int)fx;
    bool vy0 = (yi0 >= 0) & (yi0 < HH), vy1 = (yi0 + 1 >= 0) & (yi0 + 1 < HH);
    bool vx0 = (xi0 >= 0) & (xi0 < WW), vx1 = (xi0 + 1 >= 0) & (xi0 + 1 < WW);
    int ty0 = min(max(yi0 - ybase, 0), 10);   // keep 2x2 patch inside tile
    int tx0 = min(max(xi0 - xbase, 0), 22);
    union { short8 s8; short s[8]; } mp;
    mp.s[0] = (short)(ty0 * 24 + tx0);
    mp.s[1] = f2h((vy0 & vx0) ? (1.f - ly) * (1.f - lx) * msk : 0.f);
    mp.s[2] = f2h((vy0 & vx1) ? (1.f - ly) * lx * msk : 0.f);
    mp.s[3] = f2h((vy1 & vx0) ? ly * (1.f - lx) * msk : 0.f);
    mp.s[4] = f2h((vy1 & vx1) ? ly * lx * msk : 0.f);
    mp.s[5] = 0; mp.s[6] = 0; mp.s[7] = 0;
    *(short8*)&meta[i * 8] = mp.s8;
  }
  __syncthreads();

  // ---- main: wave w owns pixel-row nt=w (16 px), all 64 oc ----
  int w = t >> 6, lane = t & 63, q = lane >> 4, m = lane & 15;
  f32x4 acc[4] = {};
  const short* mbase = &meta[(w * 16 + m) * 8];

#pragma unroll 3
  for (int k = 0; k < 9; k++) {
    union { short8 s8; short s[8]; } mv;
    mv.s8 = *(const short8*)&mbase[k * 512];
    int p00 = mv.s[0];
    half2v w00 = bcast_h(mv.s[1]), w01 = bcast_h(mv.s[2]);
    half2v w10 = bcast_h(mv.s[3]), w11 = bcast_h(mv.s[4]);
    int s00 = p00, s01 = p00 + 1, s10 = p00 + 24, s11 = p00 + 25;
#pragma unroll
    for (int ch = 0; ch < 2; ch++) {
      int f = 2 * k + ch;
      int g = ch * 4 + q;
      const short* ap = wh + (f * 256 + m * 4 + q) * 8;  // [f][4][16][4][8]
      short8 a0 = *(const short8*)ap;
      short8 a1 = *(const short8*)(ap + 512);
      short8 a2 = *(const short8*)(ap + 1024);
      short8 a3 = *(const short8*)(ap + 1536);
      union { short8 s8; half2v h[4]; } c00, c01, c10, c11, bb;
      c00.s8 = *(const short8*)&xt[s00 * 64 + ((g ^ (s00 & 7)) << 3)];
      c01.s8 = *(const short8*)&xt[s01 * 64 + ((g ^ (s01 & 7)) << 3)];
      c10.s8 = *(const short8*)&xt[s10 * 64 + ((g ^ (s10 & 7)) << 3)];
      c11.s8 = *(const short8*)&xt[s11 * 64 + ((g ^ (s11 & 7)) << 3)];
#pragma unroll
      for (int d = 0; d < 4; d++)
        bb.h[d] = c00.h[d] * w00 + c01.h[d] * w01 + c10.h[d] * w10 +
                  c11.h[d] * w11;
      union { short8 s8; half8 h8; } B, A0, A1, A2, A3;
      B.s8 = bb.s8; A0.s8 = a0; A1.s8 = a1; A2.s8 = a2; A3.s8 = a3;
      acc[0] = __builtin_amdgcn_mfma_f32_16x16x32_f16(A0.h8, B.h8, acc[0], 0, 0, 0);
      acc[1] = __builtin_amdgcn_mfma_f32_16x16x32_f16(A1.h8, B.h8, acc[1], 0, 0, 0);
      acc[2] = __builtin_amdgcn_mfma_f32_16x16x32_f16(A2.h8, B.h8, acc[2], 0, 0, 0);
      acc[3] = __builtin_amdgcn_mfma_f32_16x16x32_f16(A3.h8, B.h8, acc[3], 0, 0, 0);
    }
  }

  // ---- epilogue: BN + optional residual + exact GELU ----
  int y = y0 + w, x = x0 + m;
#pragma unroll
  for (int ot = 0; ot < 4; ot++)
#pragma unroll
    for (int r = 0; r < 4; r++) {
      int oc = ot * 16 + q * 4 + r;
      size_t idx = ((size_t)(b * 64 + oc)) * HWSZ + y * WW + x;
      float v = acc[ot][r] * scale[oc] + shift[oc];
      if (identity) v += identity[idx];
      v = 0.5f * v * (1.f + erff(v * 0.70710678118654752f));
      out[idx] = v;
    }
}

// ---------------------------------------------------------------------------
extern "C" void kernel_launch(void* const* d_in, const int* in_sizes, int n_in,
                              void* d_out, int out_size, void* d_ws, size_t ws_size,
                              hipStream_t stream) {
  const float* x     = (const float*)d_in[0];
  const float* w_om1 = (const float*)d_in[1];
  const float* b_om1 = (const float*)d_in[2];
  const float* w_d1  = (const float*)d_in[3];
  const float* bn1g  = (const float*)d_in[4];
  const float* bn1b  = (const float*)d_in[5];
  const float* bn1m  = (const float*)d_in[6];
  const float* bn1v  = (const float*)d_in[7];
  const float* w_om2 = (const float*)d_in[8];
  const float* b_om2 = (const float*)d_in[9];
  const float* w_d2  = (const float*)d_in[10];
  const float* bn2g  = (const float*)d_in[11];
  const float* bn2b  = (const float*)d_in[12];
  const float* bn2m  = (const float*)d_in[13];
  const float* bn2v  = (const float*)d_in[14];

  float* ws   = (float*)d_ws;
  float* om   = ws;                       // 4*27*25600
  float* out1 = ws + 2764800;             // 4*64*25600
  float* sc   = ws + 9318400;             // 256
  short* w1h  = (short*)(ws + 9318656);   // 36864 halves
  short* w2h  = w1h + 36864;
  short* wo1h = w2h + 36864;              // 18432 halves
  short* wo2h = wo1h + 18432;
  float* outp = (float*)d_out;

  prep_kernel<<<dim3(64), dim3(256), 0, stream>>>(
      bn1g, bn1b, bn1m, bn1v, bn2g, bn2b, bn2m, bn2v,
      w_d1, w_d2, w_om1, w_om2, sc, w1h, w2h, wo1h, wo2h);

  dim3 grid(WW / 16, HH / 4, 4);

  conv27_kernel<<<grid, dim3(256), 0, stream>>>(x, wo1h, b_om1, om);
  dcn_kernel<<<grid, dim3(256), 0, stream>>>(x, om, w1h, sc, sc + 64,
                                             nullptr, out1);
  conv27_kernel<<<grid, dim3(256), 0, stream>>>(out1, wo2h, b_om2, om);
  dcn_kernel<<<grid, dim3(256), 0, stream>>>(out1, om, w2h, sc + 128, sc + 192,
                                             x, outp);
}

// Round 4
// 230.127 us; speedup vs baseline: 7.1277x; 1.8511x over previous
//
#include <hip/hip_runtime.h>
#include <math.h>

#define HH 160
#define WW 160
#define HWSZ 25600
#define TR 10
#define TC 22
#define NSLOT 220   // TR*TC tile slots, margin +-3 around 16x4 px tile

typedef __attribute__((ext_vector_type(8))) short short8;
typedef __attribute__((ext_vector_type(4))) short short4v;
typedef __attribute__((ext_vector_type(8))) _Float16 half8;
typedef __attribute__((ext_vector_type(2))) _Float16 half2v;
typedef __attribute__((ext_vector_type(4))) float f32x4;

__device__ __forceinline__ short f2h(float f) {
  union { _Float16 h; short s; } u; u.h = (_Float16)f; return u.s;
}
__device__ __forceinline__ float h2f(short s) {
  union { _Float16 h; short s; } u; u.s = s; return (float)u.h;
}
__device__ __forceinline__ half2v bcast_h(short s) {
  unsigned int x = (unsigned short)s; x |= x << 16;
  union { unsigned int u; half2v h; } v; v.u = x; return v.h;
}

// ---------------------------------------------------------------------------
// prep: BN fold + reorder+convert weights to f16 MFMA A-fragment layout.
// dcn:  [f][ot4][m16][q4][j8] = w[ot*16+m][c*9+k], kp=f*32+q*8+j, k=kp>>6,c=kp&63
// om:   [f][ot2][m16][q4][j8], oc>=27 zero-padded
__global__ __launch_bounds__(256) void prep_kernel(
    const float* __restrict__ g1, const float* __restrict__ b1,
    const float* __restrict__ m1, const float* __restrict__ v1,
    const float* __restrict__ g2, const float* __restrict__ b2,
    const float* __restrict__ m2, const float* __restrict__ v2,
    const float* __restrict__ wd1, const float* __restrict__ wd2,
    const float* __restrict__ wo1, const float* __restrict__ wo2,
    float* __restrict__ sc, short* __restrict__ wd1h, short* __restrict__ wd2h,
    short* __restrict__ wo1h, short* __restrict__ wo2h) {
  int i0 = blockIdx.x * 256 + threadIdx.x;
  int stride = gridDim.x * 256;
  for (int i = i0; i < 36864; i += stride) {
    int j = i & 7, q = (i >> 3) & 3, m = (i >> 5) & 15;
    int ot = (i >> 9) & 3, f = i >> 11;
    int kp = f * 32 + q * 8 + j;
    int k = kp >> 6, c = kp & 63;
    int src = (ot * 16 + m) * 576 + c * 9 + k;
    wd1h[i] = f2h(wd1[src]);
    wd2h[i] = f2h(wd2[src]);
  }
  for (int i = i0; i < 18432; i += stride) {
    int j = i & 7, q = (i >> 3) & 3, m = (i >> 5) & 15;
    int ot = (i >> 9) & 1, f = i >> 10;
    int kp = f * 32 + q * 8 + j;
    int k = kp >> 6, c = kp & 63;
    int oc = ot * 16 + m;
    wo1h[i] = (oc < 27) ? f2h(wo1[oc * 576 + c * 9 + k]) : (short)0;
    wo2h[i] = (oc < 27) ? f2h(wo2[oc * 576 + c * 9 + k]) : (short)0;
  }
  if (i0 < 64) {
    float s1 = g1[i0] * rsqrtf(v1[i0] + 1e-5f);
    sc[i0]       = s1;
    sc[64 + i0]  = b1[i0] - m1[i0] * s1;
    float s2 = g2[i0] * rsqrtf(v2[i0] + 1e-5f);
    sc[128 + i0] = s2;
    sc[192 + i0] = b2[i0] - m2[i0] * s2;
  }
}

// ---------------------------------------------------------------------------
// xcl: transpose x f32 NCHW -> f16 NHWC (coalesced both sides via LDS tile)
__global__ __launch_bounds__(256) void xcl_kernel(
    const float* __restrict__ x, short* __restrict__ xcl) {
  __shared__ short tmp[64][72];
  int t = threadIdx.x;
  int p0 = blockIdx.x * 64;
  int b = blockIdx.y;
  const float* xb = x + (size_t)b * 64 * HWSZ;
  for (int i = t; i < 4096; i += 256) {
    int c = i >> 6, p = i & 63;
    tmp[p][c] = f2h(xb[c * HWSZ + p0 + p]);
  }
  __syncthreads();
  short* ob = xcl + ((size_t)b * HWSZ + p0) * 64;
  for (int i = t; i < 512; i += 256) {
    int p = i >> 3, g = i & 7;
    *(short8*)&ob[p * 64 + g * 8] = *(const short8*)&tmp[p][g * 8];
  }
}

// ---------------------------------------------------------------------------
// dcn_fused: offset-conv (27ch) + modulated deform conv (64->64) + BN
//            + optional residual + GELU, all from one staged tile.
// Block: 16x * 4y px, 256 thr / 4 waves. Wave w owns pixel row y0+w.
__global__ __launch_bounds__(256, 4) void dcn_fused(
    const short* __restrict__ xcl,     // [B][HW][64] f16 NHWC
    const short* __restrict__ who,     // om weights  [f][2][16][4][8]
    const float* __restrict__ bias_om, // 27
    const short* __restrict__ whd,     // dcn weights [f][4][16][4][8]
    const float* __restrict__ scale, const float* __restrict__ shift,
    const float* __restrict__ identity,  // f32 NCHW or null
    short* __restrict__ out_cl,          // f16 NHWC (layer 1) or null
    float* __restrict__ out_f32) {       // f32 NCHW (layer 2) or null
  __shared__ short xt[NSLOT * 64];          // 28.2 KB, 16B groups swizzled
  __shared__ short omv[64 * 36];            // [px][oc] f16, 4.6 KB
  __shared__ unsigned short meta_o[576];    // top-left slot per (k,px)
  __shared__ short meta_w[576 * 4];         // 4 folded corner weights f16

  int t = threadIdx.x;
  int x0 = blockIdx.x * 16, y0 = blockIdx.y * 4, b = blockIdx.z;
  int w = t >> 6, lane = t & 63, q = lane >> 4, m = lane & 15;
  int ybase = y0 - 3, xbase = x0 - 3;

  // ---- stage tile (coalesced b128 copies) ----
  const short* xb = xcl + (size_t)b * HWSZ * 64;
  for (int i = t; i < NSLOT * 8; i += 256) {
    int slot = i >> 3, g = i & 7;
    int ty = slot / TC, tx = slot - ty * TC;
    int gy = ybase + ty, gx = xbase + tx;
    short8 v = {};
    if (gy >= 0 && gy < HH && gx >= 0 && gx < WW)
      v = *(const short8*)&xb[(gy * WW + gx) * 64 + g * 8];
    *(short8*)&xt[slot * 64 + ((g ^ (slot & 7)) << 3)] = v;
  }
  __syncthreads();

  // ---- om GEMM: wave w -> 27 oc x 16 px of row y0+w ----
  {
    f32x4 oacc0 = {}, oacc1 = {};
#pragma unroll 6
    for (int f = 0; f < 18; f++) {
      int k = f >> 1;
      int ki = k / 3, kj = k - ki * 3;
      int g = (f & 1) * 4 + q;
      int slotb = (w + ki + 2) * TC + (m + kj + 2);
      short8 bv = *(const short8*)&xt[slotb * 64 + ((g ^ (slotb & 7)) << 3)];
      const short* ap = who + (f * 128 + m * 4 + q) * 8;
      short8 a0 = *(const short8*)ap;
      short8 a1 = *(const short8*)(ap + 512);
      union { short8 s8; half8 h; } A0, A1, B;
      A0.s8 = a0; A1.s8 = a1; B.s8 = bv;
      oacc0 = __builtin_amdgcn_mfma_f32_16x16x32_f16(A0.h, B.h, oacc0, 0, 0, 0);
      oacc1 = __builtin_amdgcn_mfma_f32_16x16x32_f16(A1.h, B.h, oacc1, 0, 0, 0);
    }
    int px = w * 16 + m;
#pragma unroll
    for (int mt = 0; mt < 2; mt++) {
      f32x4 oa = mt ? oacc1 : oacc0;
      short4v pv;
#pragma unroll
      for (int r = 0; r < 4; r++) {
        int oc = mt * 16 + q * 4 + r;
        float bb = (oc < 27) ? bias_om[oc] : 0.f;
        pv[r] = f2h(oa[r] + bb);
      }
      *(short4v*)&omv[px * 36 + mt * 16 + q * 4] = pv;
    }
  }
  __syncthreads();

  // ---- meta: per (k,px) top-left slot + 4 folded corner weights ----
  for (int i = t; i < 576; i += 256) {
    int k = i >> 6, px = i & 63;
    int y = y0 + (px >> 4), x = x0 + (px & 15);
    float dy = h2f(omv[px * 36 + 2 * k]);
    float dx = h2f(omv[px * 36 + 2 * k + 1]);
    float ml = h2f(omv[px * 36 + 18 + k]);
    float msk = 1.f / (1.f + __expf(-ml));
    int ki = k / 3, kj = k - ki * 3;
    float py  = (float)(y - 1 + ki) + dy;
    float pxf = (float)(x - 1 + kj) + dx;
    float fy = floorf(py), fx = floorf(pxf);
    float ly = py - fy, lx = pxf - fx;
    int yi0 = (int)fy, xi0 = (int)fx;
    bool vy0 = (yi0 >= 0) & (yi0 < HH), vy1 = (yi0 + 1 >= 0) & (yi0 + 1 < HH);
    bool vx0 = (xi0 >= 0) & (xi0 < WW), vx1 = (xi0 + 1 >= 0) & (xi0 + 1 < WW);
    int ty0 = min(max(yi0 - ybase, 0), TR - 2);
    int tx0 = min(max(xi0 - xbase, 0), TC - 2);
    meta_o[i] = (unsigned short)(ty0 * TC + tx0);
    short4v wv;
    wv[0] = f2h((vy0 & vx0) ? (1.f - ly) * (1.f - lx) * msk : 0.f);
    wv[1] = f2h((vy0 & vx1) ? (1.f - ly) * lx * msk : 0.f);
    wv[2] = f2h((vy1 & vx0) ? ly * (1.f - lx) * msk : 0.f);
    wv[3] = f2h((vy1 & vx1) ? ly * lx * msk : 0.f);
    *(short4v*)&meta_w[i * 4] = wv;
  }
  __syncthreads();

  // ---- main GEMM: 64 oc x 16 px, K=576, bilinear fused into B-frags ----
  f32x4 acc[4] = {};
#pragma unroll 3
  for (int k = 0; k < 9; k++) {
    int mi = k * 64 + w * 16 + m;
    int p00 = meta_o[mi];
    short4v wv = *(const short4v*)&meta_w[mi * 4];
    half2v w00 = bcast_h(wv[0]), w01 = bcast_h(wv[1]);
    half2v w10 = bcast_h(wv[2]), w11 = bcast_h(wv[3]);
    int s00 = p00, s01 = p00 + 1, s10 = p00 + TC, s11 = p00 + TC + 1;
#pragma unroll
    for (int ch = 0; ch < 2; ch++) {
      int f = 2 * k + ch;
      int g = ch * 4 + q;
      const short* ap = whd + (f * 256 + m * 4 + q) * 8;
      short8 a0 = *(const short8*)ap;
      short8 a1 = *(const short8*)(ap + 512);
      short8 a2 = *(const short8*)(ap + 1024);
      short8 a3 = *(const short8*)(ap + 1536);
      union { short8 s8; half2v h[4]; } c00, c01, c10, c11, bb;
      c00.s8 = *(const short8*)&xt[s00 * 64 + ((g ^ (s00 & 7)) << 3)];
      c01.s8 = *(const short8*)&xt[s01 * 64 + ((g ^ (s01 & 7)) << 3)];
      c10.s8 = *(const short8*)&xt[s10 * 64 + ((g ^ (s10 & 7)) << 3)];
      c11.s8 = *(const short8*)&xt[s11 * 64 + ((g ^ (s11 & 7)) << 3)];
#pragma unroll
      for (int d = 0; d < 4; d++)
        bb.h[d] = c00.h[d] * w00 + c01.h[d] * w01 + c10.h[d] * w10 +
                  c11.h[d] * w11;
      union { short8 s8; half8 h8; } B, A0, A1, A2, A3;
      B.s8 = bb.s8; A0.s8 = a0; A1.s8 = a1; A2.s8 = a2; A3.s8 = a3;
      acc[0] = __builtin_amdgcn_mfma_f32_16x16x32_f16(A0.h8, B.h8, acc[0], 0, 0, 0);
      acc[1] = __builtin_amdgcn_mfma_f32_16x16x32_f16(A1.h8, B.h8, acc[1], 0, 0, 0);
      acc[2] = __builtin_amdgcn_mfma_f32_16x16x32_f16(A2.h8, B.h8, acc[2], 0, 0, 0);
      acc[3] = __builtin_amdgcn_mfma_f32_16x16x32_f16(A3.h8, B.h8, acc[3], 0, 0, 0);
    }
  }

  // ---- epilogue ----
  int y = y0 + w, x = x0 + m;
  if (out_f32) {  // layer 2: BN + residual + GELU -> f32 NCHW
#pragma unroll
    for (int ot = 0; ot < 4; ot++)
#pragma unroll
      for (int r = 0; r < 4; r++) {
        int oc = ot * 16 + q * 4 + r;
        size_t idx = ((size_t)(b * 64 + oc)) * HWSZ + y * WW + x;
        float v = acc[ot][r] * scale[oc] + shift[oc] + identity[idx];
        v = 0.5f * v * (1.f + erff(v * 0.70710678118654752f));
        out_f32[idx] = v;
      }
  } else {  // layer 1: BN + GELU -> f16 NHWC
    size_t base = ((size_t)b * HWSZ + y * WW + x) * 64;
#pragma unroll
    for (int ot = 0; ot < 4; ot++) {
      short4v pv;
#pragma unroll
      for (int r = 0; r < 4; r++) {
        int oc = ot * 16 + q * 4 + r;
        float v = acc[ot][r] * scale[oc] + shift[oc];
        v = 0.5f * v * (1.f + erff(v * 0.70710678118654752f));
        pv[r] = f2h(v);
      }
      *(short4v*)&out_cl[base + ot * 16 + q * 4] = pv;
    }
  }
}

// ---------------------------------------------------------------------------
extern "C" void kernel_launch(void* const* d_in, const int* in_sizes, int n_in,
                              void* d_out, int out_size, void* d_ws, size_t ws_size,
                              hipStream_t stream) {
  const float* x     = (const float*)d_in[0];
  const float* w_om1 = (const float*)d_in[1];
  const float* b_om1 = (const float*)d_in[2];
  const float* w_d1  = (const float*)d_in[3];
  const float* bn1g  = (const float*)d_in[4];
  const float* bn1b  = (const float*)d_in[5];
  const float* bn1m  = (const float*)d_in[6];
  const float* bn1v  = (const float*)d_in[7];
  const float* w_om2 = (const float*)d_in[8];
  const float* b_om2 = (const float*)d_in[9];
  const float* w_d2  = (const float*)d_in[10];
  const float* bn2g  = (const float*)d_in[11];
  const float* bn2b  = (const float*)d_in[12];
  const float* bn2m  = (const float*)d_in[13];
  const float* bn2v  = (const float*)d_in[14];

  float* ws    = (float*)d_ws;
  float* sc    = ws;                       // 256 f
  short* w1h   = (short*)(ws + 256);       // 36864 halves
  short* w2h   = w1h + 36864;
  short* wo1h  = w2h + 36864;              // 18432 halves
  short* wo2h  = wo1h + 18432;
  short* x_cl  = (short*)(ws + 55552);     // 6,553,600 halves (13.1 MB)
  short* o1_cl = x_cl + 6553600;           // 6,553,600 halves
  float* outp  = (float*)d_out;

  prep_kernel<<<dim3(64), dim3(256), 0, stream>>>(
      bn1g, bn1b, bn1m, bn1v, bn2g, bn2b, bn2m, bn2v,
      w_d1, w_d2, w_om1, w_om2, sc, w1h, w2h, wo1h, wo2h);
  xcl_kernel<<<dim3(HWSZ / 64, 4), dim3(256), 0, stream>>>(x, x_cl);

  dim3 grid(WW / 16, HH / 4, 4);
  dcn_fused<<<grid, dim3(256), 0, stream>>>(
      x_cl, wo1h, b_om1, w1h, sc, sc + 64, nullptr, o1_cl, nullptr);
  dcn_fused<<<grid, dim3(256), 0, stream>>>(
      o1_cl, wo2h, b_om2, w2h, sc + 128, sc + 192, x, nullptr, outp);
}

// Round 7
// 222.392 us; speedup vs baseline: 7.3756x; 1.0348x over previous
//
#include <hip/hip_runtime.h>
#include <math.h>

#define HH 160
#define WW 160
#define HWSZ 25600
#define TR 10
#define TC 22
#define NSLOT 220   // TR*TC tile slots, margin +-3 around 16x4 px tile

typedef __attribute__((ext_vector_type(8))) short short8;
typedef __attribute__((ext_vector_type(4))) short short4v;
typedef __attribute__((ext_vector_type(8))) _Float16 half8;
typedef __attribute__((ext_vector_type(2))) _Float16 half2v;
typedef __attribute__((ext_vector_type(4))) float f32x4;

__device__ __forceinline__ short f2h(float f) {
  union { _Float16 h; short s; } u; u.h = (_Float16)f; return u.s;
}
__device__ __forceinline__ float h2f(short s) {
  union { _Float16 h; short s; } u; u.s = s; return (float)u.h;
}
__device__ __forceinline__ half2v bcast_h(short s) {
  unsigned int x = (unsigned short)s; x |= x << 16;
  union { unsigned int u; half2v h; } v; v.u = x; return v.h;
}

// ---------------------------------------------------------------------------
// prep: BN fold + reorder+convert weights to f16 MFMA A-fragment layout.
// dcn:  [f18][ot4][m16][q4][j8] = w[ot*16+m][c*9+k], kp=f*32+q*8+j
// om:   [f18][ot2][m16][q4][j8], oc>=27 zero-padded
__global__ __launch_bounds__(256) void prep_kernel(
    const float* __restrict__ g1, const float* __restrict__ b1,
    const float* __restrict__ m1, const float* __restrict__ v1,
    const float* __restrict__ g2, const float* __restrict__ b2,
    const float* __restrict__ m2, const float* __restrict__ v2,
    const float* __restrict__ wd1, const float* __restrict__ wd2,
    const float* __restrict__ wo1, const float* __restrict__ wo2,
    float* __restrict__ sc, short* __restrict__ wd1h, short* __restrict__ wd2h,
    short* __restrict__ wo1h, short* __restrict__ wo2h) {
  int i0 = blockIdx.x * 256 + threadIdx.x;
  int stride = gridDim.x * 256;
  for (int i = i0; i < 36864; i += stride) {
    int j = i & 7, q = (i >> 3) & 3, m = (i >> 5) & 15;
    int ot = (i >> 9) & 3, f = i >> 11;
    int kp = f * 32 + q * 8 + j;
    int k = kp >> 6, c = kp & 63;
    int src = (ot * 16 + m) * 576 + c * 9 + k;
    wd1h[i] = f2h(wd1[src]);
    wd2h[i] = f2h(wd2[src]);
  }
  for (int i = i0; i < 18432; i += stride) {
    int j = i & 7, q = (i >> 3) & 3, m = (i >> 5) & 15;
    int ot = (i >> 9) & 1, f = i >> 10;
    int kp = f * 32 + q * 8 + j;
    int k = kp >> 6, c = kp & 63;
    int oc = ot * 16 + m;
    wo1h[i] = (oc < 27) ? f2h(wo1[oc * 576 + c * 9 + k]) : (short)0;
    wo2h[i] = (oc < 27) ? f2h(wo2[oc * 576 + c * 9 + k]) : (short)0;
  }
  if (i0 < 64) {
    float s1 = g1[i0] * rsqrtf(v1[i0] + 1e-5f);
    sc[i0]       = s1;
    sc[64 + i0]  = b1[i0] - m1[i0] * s1;
    float s2 = g2[i0] * rsqrtf(v2[i0] + 1e-5f);
    sc[128 + i0] = s2;
    sc[192 + i0] = b2[i0] - m2[i0] * s2;
  }
}

// ---------------------------------------------------------------------------
// xcl: transpose x f32 NCHW -> f16 NHWC (coalesced both sides via LDS tile)
__global__ __launch_bounds__(256) void xcl_kernel(
    const float* __restrict__ x, short* __restrict__ xcl) {
  __shared__ short tmp[64][72];
  int t = threadIdx.x;
  int p0 = blockIdx.x * 64;
  int b = blockIdx.y;
  const float* xb = x + (size_t)b * 64 * HWSZ;
  for (int i = t; i < 4096; i += 256) {
    int c = i >> 6, p = i & 63;
    tmp[p][c] = f2h(xb[c * HWSZ + p0 + p]);
  }
  __syncthreads();
  short* ob = xcl + ((size_t)b * HWSZ + p0) * 64;
  for (int i = t; i < 512; i += 256) {
    int p = i >> 3, g = i & 7;
    *(short8*)&ob[p * 64 + g * 8] = *(const short8*)&tmp[p][g * 8];
  }
}

// ---------------------------------------------------------------------------
// dcn_fused: offset-conv (27ch) + modulated deform conv (64->64) + BN
//            + optional residual + GELU, all from one staged tile.
// Block: 16x * 4y px, 256 thr / 4 waves. Wave w owns pixel row y0+w.
// Main-loop A-weights staged per-tap through LDS (As), cutting per-block
// global A traffic 288 KB -> 72 KB (R4 was ~75% of the L2 BW ceiling).
__global__ __launch_bounds__(256, 3) void dcn_fused(
    const short* __restrict__ xcl,     // [B][HW][64] f16 NHWC
    const short* __restrict__ who,     // om weights  [f][2][16][4][8]
    const float* __restrict__ bias_om, // 27
    const short* __restrict__ whd,     // dcn weights [f][4][16][4][8]
    const float* __restrict__ scale, const float* __restrict__ shift,
    const float* __restrict__ identity,  // f32 NCHW or null
    short* __restrict__ out_cl,          // f16 NHWC (layer 1) or null
    float* __restrict__ out_f32) {       // f32 NCHW (layer 2) or null
  __shared__ short xt[NSLOT * 64];          // 28.2 KB, 16B groups swizzled
  __shared__ short omv[64 * 36];            // [px][oc] f16, 4.6 KB
  __shared__ unsigned short meta_o[576];    // top-left slot per (k,px)
  __shared__ short meta_w[576 * 4];         // 4 folded corner weights f16
  __shared__ __align__(16) short As[4096];  // per-tap A panels f=2k,2k+1 (8KB)

  int t = threadIdx.x;
  int x0 = blockIdx.x * 16, y0 = blockIdx.y * 4, b = blockIdx.z;
  int w = t >> 6, lane = t & 63, q = lane >> 4, m = lane & 15;
  int ybase = y0 - 3, xbase = x0 - 3;

  // ---- stage tile (coalesced b128 copies) ----
  const short* xb = xcl + (size_t)b * HWSZ * 64;
  for (int i = t; i < NSLOT * 8; i += 256) {
    int slot = i >> 3, g = i & 7;
    int ty = slot / TC, tx = slot - ty * TC;
    int gy = ybase + ty, gx = xbase + tx;
    short8 v = {};
    if (gy >= 0 && gy < HH && gx >= 0 && gx < WW)
      v = *(const short8*)&xb[(gy * WW + gx) * 64 + g * 8];
    *(short8*)&xt[slot * 64 + ((g ^ (slot & 7)) << 3)] = v;
  }
  __syncthreads();

  // ---- om GEMM: wave w -> 27 oc x 16 px of row y0+w -> omv ----
  {
    f32x4 oacc0 = {}, oacc1 = {};
#pragma unroll 6
    for (int f = 0; f < 18; f++) {
      int k = f >> 1;
      int ki = k / 3, kj = k - ki * 3;
      int g = (f & 1) * 4 + q;
      int slotb = (w + ki + 2) * TC + (m + kj + 2);
      short8 bv = *(const short8*)&xt[slotb * 64 + ((g ^ (slotb & 7)) << 3)];
      const short* ap = who + (f * 128 + m * 4 + q) * 8;
      short8 a0 = *(const short8*)ap;
      short8 a1 = *(const short8*)(ap + 512);
      union { short8 s8; half8 h; } A0, A1, B;
      A0.s8 = a0; A1.s8 = a1; B.s8 = bv;
      oacc0 = __builtin_amdgcn_mfma_f32_16x16x32_f16(A0.h, B.h, oacc0, 0, 0, 0);
      oacc1 = __builtin_amdgcn_mfma_f32_16x16x32_f16(A1.h, B.h, oacc1, 0, 0, 0);
    }
    int px = w * 16 + m;
#pragma unroll
    for (int mt = 0; mt < 2; mt++) {
      f32x4 oa = mt ? oacc1 : oacc0;
      short4v pv;
#pragma unroll
      for (int r = 0; r < 4; r++) {
        int oc = mt * 16 + q * 4 + r;
        float bb = (oc < 27) ? bias_om[oc] : 0.f;
        pv[r] = f2h(oa[r] + bb);
      }
      *(short4v*)&omv[px * 36 + mt * 16 + q * 4] = pv;
    }
  }
  __syncthreads();

  // ---- meta: per (k,px) top-left slot + 4 folded corner weights ----
  for (int i = t; i < 576; i += 256) {
    int k = i >> 6, px = i & 63;
    int y = y0 + (px >> 4), x = x0 + (px & 15);
    float dy = h2f(omv[px * 36 + 2 * k]);
    float dx = h2f(omv[px * 36 + 2 * k + 1]);
    float ml = h2f(omv[px * 36 + 18 + k]);
    float msk = 1.f / (1.f + __expf(-ml));
    int ki = k / 3, kj = k - ki * 3;
    float py  = (float)(y - 1 + ki) + dy;
    float pxf = (float)(x - 1 + kj) + dx;
    float fy = floorf(py), fx = floorf(pxf);
    float ly = py - fy, lx = pxf - fx;
    int yi0 = (int)fy, xi0 = (int)fx;
    bool vy0 = (yi0 >= 0) & (yi0 < HH), vy1 = (yi0 + 1 >= 0) & (yi0 + 1 < HH);
    bool vx0 = (xi0 >= 0) & (xi0 < WW), vx1 = (xi0 + 1 >= 0) & (xi0 + 1 < WW);
    int ty0 = min(max(yi0 - ybase, 0), TR - 2);
    int tx0 = min(max(xi0 - xbase, 0), TC - 2);
    meta_o[i] = (unsigned short)(ty0 * TC + tx0);
    short4v wv;
    wv[0] = f2h((vy0 & vx0) ? (1.f - ly) * (1.f - lx) * msk : 0.f);
    wv[1] = f2h((vy0 & vx1) ? (1.f - ly) * lx * msk : 0.f);
    wv[2] = f2h((vy1 & vx0) ? ly * (1.f - lx) * msk : 0.f);
    wv[3] = f2h((vy1 & vx1) ? ly * lx * msk : 0.f);
    *(short4v*)&meta_w[i * 4] = wv;
  }
  __syncthreads();

  // ---- main GEMM: 64 oc x 16 px, K=576, bilinear fused into B-frags.
  //      A panel for tap k (f=2k,2k+1; 4096 shorts) staged in LDS. ----
  f32x4 acc[4] = {};
  for (int k = 0; k < 9; k++) {
    __syncthreads();  // prior tap's As readers done
    {
      int i = t * 16;
      *(short8*)&As[i]     = *(const short8*)&whd[k * 4096 + i];
      *(short8*)&As[i + 8] = *(const short8*)&whd[k * 4096 + i + 8];
    }
    __syncthreads();  // As visible

    int mi = k * 64 + w * 16 + m;
    int p00 = meta_o[mi];
    short4v wv = *(const short4v*)&meta_w[mi * 4];
    half2v w00 = bcast_h(wv[0]), w01 = bcast_h(wv[1]);
    half2v w10 = bcast_h(wv[2]), w11 = bcast_h(wv[3]);
    int s00 = p00, s01 = p00 + 1, s10 = p00 + TC, s11 = p00 + TC + 1;
#pragma unroll
    for (int ch = 0; ch < 2; ch++) {
      int g = ch * 4 + q;
      const short* ap = As + ch * 2048 + m * 32 + q * 8;
      short8 a0 = *(const short8*)ap;
      short8 a1 = *(const short8*)(ap + 512);
      short8 a2 = *(const short8*)(ap + 1024);
      short8 a3 = *(const short8*)(ap + 1536);
      union { short8 s8; half2v h[4]; } c00, c01, c10, c11, bb;
      c00.s8 = *(const short8*)&xt[s00 * 64 + ((g ^ (s00 & 7)) << 3)];
      c01.s8 = *(const short8*)&xt[s01 * 64 + ((g ^ (s01 & 7)) << 3)];
      c10.s8 = *(const short8*)&xt[s10 * 64 + ((g ^ (s10 & 7)) << 3)];
      c11.s8 = *(const short8*)&xt[s11 * 64 + ((g ^ (s11 & 7)) << 3)];
#pragma unroll
      for (int d = 0; d < 4; d++)
        bb.h[d] = c00.h[d] * w00 + c01.h[d] * w01 + c10.h[d] * w10 +
                  c11.h[d] * w11;
      union { short8 s8; half8 h8; } B, A0, A1, A2, A3;
      B.s8 = bb.s8; A0.s8 = a0; A1.s8 = a1; A2.s8 = a2; A3.s8 = a3;
      acc[0] = __builtin_amdgcn_mfma_f32_16x16x32_f16(A0.h8, B.h8, acc[0], 0, 0, 0);
      acc[1] = __builtin_amdgcn_mfma_f32_16x16x32_f16(A1.h8, B.h8, acc[1], 0, 0, 0);
      acc[2] = __builtin_amdgcn_mfma_f32_16x16x32_f16(A2.h8, B.h8, acc[2], 0, 0, 0);
      acc[3] = __builtin_amdgcn_mfma_f32_16x16x32_f16(A3.h8, B.h8, acc[3], 0, 0, 0);
    }
  }

  // ---- epilogue ----
  // D layout: acc[ot] = oc tile ot; oc = ot*16 + q*4 + r; px col = m, row = w
  int y = y0 + w, x = x0 + m;
  if (out_f32) {  // layer 2: BN + residual + GELU -> f32 NCHW
#pragma unroll
    for (int ot = 0; ot < 4; ot++)
#pragma unroll
      for (int r = 0; r < 4; r++) {
        int oc = ot * 16 + q * 4 + r;
        size_t idx = ((size_t)(b * 64 + oc)) * HWSZ + y * WW + x;
        float v = acc[ot][r] * scale[oc] + shift[oc] + identity[idx];
        v = 0.5f * v * (1.f + erff(v * 0.70710678118654752f));
        out_f32[idx] = v;
      }
  } else {  // layer 1: BN + GELU -> f16 NHWC
    size_t base = ((size_t)b * HWSZ + y * WW + x) * 64;
#pragma unroll
    for (int ot = 0; ot < 4; ot++) {
      short4v pv;
#pragma unroll
      for (int r = 0; r < 4; r++) {
        int oc = ot * 16 + q * 4 + r;
        float v = acc[ot][r] * scale[oc] + shift[oc];
        v = 0.5f * v * (1.f + erff(v * 0.70710678118654752f));
        pv[r] = f2h(v);
      }
      *(short4v*)&out_cl[base + ot * 16 + q * 4] = pv;
    }
  }
}

// ---------------------------------------------------------------------------
extern "C" void kernel_launch(void* const* d_in, const int* in_sizes, int n_in,
                              void* d_out, int out_size, void* d_ws, size_t ws_size,
                              hipStream_t stream) {
  const float* x     = (const float*)d_in[0];
  const float* w_om1 = (const float*)d_in[1];
  const float* b_om1 = (const float*)d_in[2];
  const float* w_d1  = (const float*)d_in[3];
  const float* bn1g  = (const float*)d_in[4];
  const float* bn1b  = (const float*)d_in[5];
  const float* bn1m  = (const float*)d_in[6];
  const float* bn1v  = (const float*)d_in[7];
  const float* w_om2 = (const float*)d_in[8];
  const float* b_om2 = (const float*)d_in[9];
  const float* w_d2  = (const float*)d_in[10];
  const float* bn2g  = (const float*)d_in[11];
  const float* bn2b  = (const float*)d_in[12];
  const float* bn2m  = (const float*)d_in[13];
  const float* bn2v  = (const float*)d_in[14];

  float* ws    = (float*)d_ws;
  float* sc    = ws;                       // 256 f
  short* w1h   = (short*)(ws + 256);       // 36864 halves
  short* w2h   = w1h + 36864;
  short* wo1h  = w2h + 36864;              // 18432 halves
  short* wo2h  = wo1h + 18432;
  short* x_cl  = (short*)(ws + 55552);     // 6,553,600 halves
  short* o1_cl = x_cl + 6553600;           // 6,553,600 halves
  float* outp  = (float*)d_out;

  prep_kernel<<<dim3(64), dim3(256), 0, stream>>>(
      bn1g, bn1b, bn1m, bn1v, bn2g, bn2b, bn2m, bn2v,
      w_d1, w_d2, w_om1, w_om2, sc, w1h, w2h, wo1h, wo2h);
  xcl_kernel<<<dim3(HWSZ / 64, 4), dim3(256), 0, stream>>>(x, x_cl);

  dim3 grid(WW / 16, HH / 4, 4);
  dcn_fused<<<grid, dim3(256), 0, stream>>>(
      x_cl, wo1h, b_om1, w1h, sc, sc + 64, nullptr, o1_cl, nullptr);
  dcn_fused<<<grid, dim3(256), 0, stream>>>(
      o1_cl, wo2h, b_om2, w2h, sc + 128, sc + 192, x, nullptr, outp);
}